// Round 6
// baseline (267.893 us; speedup 1.0000x reference)
//
#include <hip/hip_runtime.h>
#include <stdint.h>

typedef _Float16 half8  __attribute__((ext_vector_type(8)));
typedef _Float16 half4v __attribute__((ext_vector_type(4)));
typedef float    floatx4 __attribute__((ext_vector_type(4)));

#define LOG2E 1.44269504088896340736f

// async global->LDS 16B copy (LDS dest must be wave-uniform base + lane*16)
__device__ __forceinline__ void gl_lds16(const _Float16* g, _Float16* l) {
  __builtin_amdgcn_global_load_lds(
      (__attribute__((address_space(1))) void*)g,
      (__attribute__((address_space(3))) void*)l, 16, 0, 0);
}
__device__ __forceinline__ void gl_lds16f(const float* g, float* l) {
  __builtin_amdgcn_global_load_lds(
      (__attribute__((address_space(1))) void*)g,
      (__attribute__((address_space(3))) void*)l, 16, 0, 0);
}

__device__ __forceinline__ half4v pack4(float a, float b, float c, float d) {
  auto lo = __builtin_amdgcn_cvt_pkrtz(a, b);
  auto hi = __builtin_amdgcn_cvt_pkrtz(c, d);
  return half4v{static_cast<_Float16>(lo[0]), static_cast<_Float16>(lo[1]),
                static_cast<_Float16>(hi[0]), static_cast<_Float16>(hi[1])};
}
__device__ __forceinline__ half8 cvt8(floatx4 a, floatx4 b) {
  half4v lo = pack4(a[0], a[1], a[2], a[3]);
  half4v hi = pack4(b[0], b[1], b[2], b[3]);
  return __builtin_shufflevector(lo, hi, 0, 1, 2, 3, 4, 5, 6, 7);
}

// ---------------- kernel 1: fp32 -> f16 convert (weights only) ----------------
struct CvtArgs {
  const float* src[3];
  _Float16*    dst[3];
};

__global__ void cvt_kernel(CvtArgs a) {
  const int z = blockIdx.y;
  const int i = (blockIdx.x * 256 + threadIdx.x) * 8;
  const float4* s = (const float4*)(a.src[z] + i);
  float4 v0 = s[0], v1 = s[1];
  half8 h = { (_Float16)v0.x, (_Float16)v0.y, (_Float16)v0.z, (_Float16)v0.w,
              (_Float16)v1.x, (_Float16)v1.y, (_Float16)v1.z, (_Float16)v1.w };
  *(half8*)(a.dst[z] + i) = h;
}

// ---------------- kernel 2: QKV projection GEMM -----------------
// C[m,n] = X[m,:] . W[n,:] + b[n]; X staged fp32 (converted in-register),
// W staged f16. Both LDS tiles XOR-granule-swizzled (A: g^(r&7) on 8-granule
// rows; B: g^((r>>1)&3) on 4-granule rows) -> frag ds_read_b128 is ~2-way
// (free) instead of 8-16-way conflicted. K-loop double-buffered: stage k+1
// before computing k (prefetch lands before the barrier drain).
// z=0: Q -> [48][2048][64]*log2e ; z=1: K ; z=2: V^T [48][64][2048].

__device__ __forceinline__ void gemm_stage(const float* __restrict__ X,
                                           const _Float16* __restrict__ W,
                                           float* Asb, _Float16* Bsb,
                                           int m0, int n0, int k0, int tid) {
  #pragma unroll
  for (int i = 0; i < 4; ++i) {          // A: 128 rows x 32 fp32 = 16KB
    int G = i * 256 + tid;
    int r = G >> 3, gl = G & 7;
    int g = gl ^ (r & 7);
    gl_lds16f(X + (size_t)(m0 + r) * 768 + k0 + g * 4, Asb + G * 4);
  }
  #pragma unroll
  for (int i = 0; i < 2; ++i) {          // B: 128 rows x 32 f16 = 8KB
    int G = i * 256 + tid;
    int r = G >> 2, gl = G & 3;
    int g = gl ^ ((r >> 1) & 3);
    gl_lds16(W + (size_t)(n0 + r) * 768 + k0 + g * 8, Bsb + G * 8);
  }
}

template <int BUF>
__device__ __forceinline__ void gemm_body(
    int knext, const float* __restrict__ X, const _Float16* __restrict__ W,
    float* As, _Float16* Bs, int m0, int n0, int tid, int z,
    int wr, int wc, int qd, int col, floatx4 (&acc)[4][4])
{
  if (knext < 768)
    gemm_stage(X, W, As + (1 - BUF) * 4096, Bs + (1 - BUF) * 4096, m0, n0, knext, tid);

  half8 af[4], bf[4];
  #pragma unroll
  for (int t = 0; t < 4; ++t) {
    int ra = wr * 64 + t * 16 + col;
    const float* Ab = As + BUF * 4096 + ra * 32;
    floatx4 a0 = *(const floatx4*)(Ab + (((2 * qd)     ^ (ra & 7)) * 4));
    floatx4 a1 = *(const floatx4*)(Ab + (((2 * qd + 1) ^ (ra & 7)) * 4));
    af[t] = cvt8(a0, a1);
  }
  #pragma unroll
  for (int t = 0; t < 4; ++t) {
    int rb = wc * 64 + t * 16 + col;
    bf[t] = *(const half8*)(Bs + BUF * 4096 + rb * 32 + ((qd ^ ((rb >> 1) & 3)) * 8));
  }
  if (z == 2) {
    #pragma unroll
    for (int i = 0; i < 4; ++i)
      #pragma unroll
      for (int j = 0; j < 4; ++j)
        acc[i][j] = __builtin_amdgcn_mfma_f32_16x16x32_f16(af[i], bf[j], acc[i][j], 0, 0, 0);
  } else {
    #pragma unroll
    for (int i = 0; i < 4; ++i)
      #pragma unroll
      for (int j = 0; j < 4; ++j)
        acc[i][j] = __builtin_amdgcn_mfma_f32_16x16x32_f16(bf[j], af[i], acc[i][j], 0, 0, 0);
  }
  __syncthreads();
}

__global__ __launch_bounds__(256, 2) void qkv_gemm(
    const float* __restrict__ qx, const float* __restrict__ kx, const float* __restrict__ vx,
    const _Float16* __restrict__ wh,
    const float* __restrict__ bqp, const float* __restrict__ bkp, const float* __restrict__ bvp,
    _Float16* __restrict__ oq, _Float16* __restrict__ ok, _Float16* __restrict__ ovt)
{
  __shared__ __attribute__((aligned(16))) float    As[2 * 4096];
  __shared__ __attribute__((aligned(16))) _Float16 Bs[2 * 4096];
  const int z  = blockIdx.z;
  const float* X = (z == 0) ? qx : ((z == 1) ? kx : vx);
  const _Float16* W = wh + (size_t)z * 589824;
  const int m0 = blockIdx.x * 128, n0 = blockIdx.y * 128;
  const int tid  = threadIdx.x;
  const int lane = tid & 63, wid = tid >> 6;
  const int wr = wid >> 1, wc = wid & 1;
  const int qd = lane >> 4, col = lane & 15;

  const floatx4 z4 = {0.f, 0.f, 0.f, 0.f};
  floatx4 acc[4][4];
  #pragma unroll
  for (int i = 0; i < 4; ++i)
    #pragma unroll
    for (int j = 0; j < 4; ++j) acc[i][j] = z4;

  gemm_stage(X, W, As, Bs, m0, n0, 0, tid);
  __syncthreads();
  for (int kk = 0; kk < 768; kk += 64) {
    gemm_body<0>(kk + 32, X, W, As, Bs, m0, n0, tid, z, wr, wc, qd, col, acc);
    gemm_body<1>(kk + 64, X, W, As, Bs, m0, n0, tid, z, wr, wc, qd, col, acc);
  }

  const float* bias = (z == 0) ? bqp : ((z == 1) ? bkp : bvp);
  if (z == 2) {
    // V transposed: vt[(b*768 + n)*2048 + s]; lane's 4 regs = 4 consecutive seq rows -> 8B store
    #pragma unroll
    for (int j = 0; j < 4; ++j) {
      int n = n0 + wc * 64 + j * 16 + col;
      float bb = bias[n];
      #pragma unroll
      for (int i = 0; i < 4; ++i) {
        int m = m0 + wr * 64 + i * 16 + qd * 4;
        int b = m >> 11, s = m & 2047;
        half4v h;
        #pragma unroll
        for (int r = 0; r < 4; ++r) h[r] = (_Float16)(acc[i][j][r] + bb);
        *(half4v*)(ovt + ((size_t)(b * 768 + n)) * 2048 + s) = h;
      }
    }
  } else {
    // swapped orientation: col=seq, reg=4 consecutive d. One 8B store per (i,j).
    _Float16* O = (z == 0) ? oq : ok;
    const float scale = (z == 0) ? LOG2E : 1.0f;   // fold log2e into Q for exp2-domain softmax
    #pragma unroll
    for (int j = 0; j < 4; ++j) {
      int n = n0 + wc * 64 + j * 16 + qd * 4;       // 4 consecutive features
      float4 bb = *(const float4*)(bias + n);
      int hh = n >> 6, d = n & 63;
      #pragma unroll
      for (int i = 0; i < 4; ++i) {
        int m = m0 + wr * 64 + i * 16 + col;
        int b = m >> 11, s = m & 2047;
        half4v h;
        h[0] = (_Float16)((acc[i][j][0] + bb.x) * scale);
        h[1] = (_Float16)((acc[i][j][1] + bb.y) * scale);
        h[2] = (_Float16)((acc[i][j][2] + bb.z) * scale);
        h[3] = (_Float16)((acc[i][j][3] + bb.w) * scale);
        *(half4v*)(O + (size_t)(b * 12 + hh) * 131072 + (size_t)s * 64 + d) = h;
      }
    }
  }
}

// ---------------- kernel 3: flash attention -----------------
// S^T = K.Q^T with C pre-seeded with -m (negm). pf = exp2(st - mr) on a single
// path (mr usually 0); rare-max branch only rescales live regs. l rides the MFMA
// pipe as a ones-row 16x16x16 accumulator. PV B-operand == S^T C-layout.

__device__ __forceinline__ void stage_kv(const _Float16* __restrict__ Kg,
                                         const _Float16* __restrict__ Vg,
                                         _Float16* ksd, _Float16* vsd, int j0, int tid) {
  #pragma unroll
  for (int i = 0; i < 2; ++i) {
    int c = i * 256 + tid;
    int row = c >> 3, sc = c & 7;
    gl_lds16(Kg + (size_t)(j0 + row) * 64 + ((sc ^ (row & 7)) * 8), ksd + c * 8);
    gl_lds16(Vg + (size_t)row * 2048 + j0 + ((sc ^ (row & 7)) * 8), vsd + c * 8);
  }
}

template <int BUF>
__device__ __forceinline__ void attn_body(
    int jnext, const _Float16* __restrict__ Kg, const _Float16* __restrict__ Vg,
    _Float16* Ks, _Float16* Vs, int tid,
    const half8 (&qf)[2][2], int kb0, int kb1, const int (&vb)[4],
    floatx4 (&negm)[2], floatx4 (&ol)[2], floatx4 (&o)[4][2])
{
  if (jnext < 2048)
    stage_kv(Kg, Vg, Ks + (1 - BUF) * 4096, Vs + (1 - BUF) * 4096, jnext, tid);

  const char* ksb = (const char*)Ks;
  const char* vsb = (const char*)Vs;

  // S^T - m = K . Q^T + (-m) : C seeded with negm, contraction d=64 in 2 steps
  floatx4 st[4][2];
  #pragma unroll
  for (int t = 0; t < 4; ++t) {
    half8 kf0 = *(const half8*)(ksb + BUF * 8192 + t * 2048 + kb0);
    half8 kf1 = *(const half8*)(ksb + BUF * 8192 + t * 2048 + kb1);
    #pragma unroll
    for (int qt = 0; qt < 2; ++qt) {
      st[t][qt] = __builtin_amdgcn_mfma_f32_16x16x32_f16(kf0, qf[qt][0], negm[qt], 0, 0, 0);
      st[t][qt] = __builtin_amdgcn_mfma_f32_16x16x32_f16(kf1, qf[qt][1], st[t][qt], 0, 0, 0);
    }
  }

  // tile max of (s - m); mr>0 only when running max must update (rare after warm-up)
  float mr[2];
  #pragma unroll
  for (int qt = 0; qt < 2; ++qt) {
    float v = fmaxf(
        fmaxf(fmaxf(fmaxf(st[0][qt][0], st[0][qt][1]), fmaxf(st[0][qt][2], st[0][qt][3])),
              fmaxf(fmaxf(st[1][qt][0], st[1][qt][1]), fmaxf(st[1][qt][2], st[1][qt][3]))),
        fmaxf(fmaxf(fmaxf(st[2][qt][0], st[2][qt][1]), fmaxf(st[2][qt][2], st[2][qt][3])),
              fmaxf(fmaxf(st[3][qt][0], st[3][qt][1]), fmaxf(st[3][qt][2], st[3][qt][3]))));
    v = fmaxf(v, __shfl_xor(v, 16, 64));
    v = fmaxf(v, __shfl_xor(v, 32, 64));
    mr[qt] = fmaxf(v, 0.f);
  }

  // single pf path (consumes st immediately; mr is usually 0)
  half4v pf[4][2];
  #pragma unroll
  for (int qt = 0; qt < 2; ++qt)
    #pragma unroll
    for (int t = 0; t < 4; ++t)
      pf[t][qt] = pack4(__builtin_amdgcn_exp2f(st[t][qt][0] - mr[qt]),
                        __builtin_amdgcn_exp2f(st[t][qt][1] - mr[qt]),
                        __builtin_amdgcn_exp2f(st[t][qt][2] - mr[qt]),
                        __builtin_amdgcn_exp2f(st[t][qt][3] - mr[qt]));

  // rare rescale: touches only already-live registers
  if (__any(mr[0] > 0.f || mr[1] > 0.f)) {
    #pragma unroll
    for (int qt = 0; qt < 2; ++qt) {
      float al = __builtin_amdgcn_exp2f(-mr[qt]);
      negm[qt] -= mr[qt];
      ol[qt] *= al;
      #pragma unroll
      for (int dt = 0; dt < 4; ++dt) o[dt][qt] *= al;
    }
  }

  // PV: out^T = V^T . P (K=16, P straight from regs) + ones-row MFMA accumulates l
  const half4v vone = {(_Float16)1.0f, (_Float16)1.0f, (_Float16)1.0f, (_Float16)1.0f};
  #pragma unroll
  for (int dt = 0; dt < 4; ++dt) {
    #pragma unroll
    for (int t = 0; t < 4; ++t) {
      half4v vf = *(const half4v*)(vsb + BUF * 8192 + dt * 2048 + vb[t]);
      #pragma unroll
      for (int qt = 0; qt < 2; ++qt)
        o[dt][qt] = __builtin_amdgcn_mfma_f32_16x16x16f16(vf, pf[t][qt], o[dt][qt], 0, 0, 0);
    }
  }
  #pragma unroll
  for (int t = 0; t < 4; ++t)
    #pragma unroll
    for (int qt = 0; qt < 2; ++qt)
      ol[qt] = __builtin_amdgcn_mfma_f32_16x16x16f16(vone, pf[t][qt], ol[qt], 0, 0, 0);

  __syncthreads();
}

__global__ __launch_bounds__(256, 3) void attn_kernel(
    const _Float16* __restrict__ Qm,   // [48][2048][64] (log2e-scaled)
    const _Float16* __restrict__ Km,   // [48][2048][64]
    const _Float16* __restrict__ Vt,   // [48][64][2048]
    float* __restrict__ out)           // [4][2048][768]
{
  __shared__ __attribute__((aligned(16))) _Float16 Ks[2 * 4096];
  __shared__ __attribute__((aligned(16))) _Float16 Vs[2 * 4096];
  const int bh = blockIdx.y;
  const int q0 = blockIdx.x * 128;
  const int tid = threadIdx.x, lane = tid & 63, w = tid >> 6;
  const int qd = lane >> 4, col = lane & 15, c7 = col & 7;
  const _Float16* Qg = Qm + (size_t)bh * 131072;
  const _Float16* Kg = Km + (size_t)bh * 131072;
  const _Float16* Vg = Vt + (size_t)bh * 131072;

  // Q fragments direct from global (kept in regs for the whole kernel)
  half8 qf[2][2];
  #pragma unroll
  for (int qt = 0; qt < 2; ++qt)
    #pragma unroll
    for (int ks = 0; ks < 2; ++ks)
      qf[qt][ks] = *(const half8*)(Qg + (size_t)(q0 + w * 32 + qt * 16 + col) * 64
                                   + (ks * 4 + qd) * 8);

  // loop-invariant per-lane LDS byte offsets (tile offsets fold into ds_read immediates)
  const int kb0 = col * 128 + ((qd ^ c7) * 16);
  const int kb1 = col * 128 + (((4 + qd) ^ c7) * 16);
  const int vq = (qd >> 1) ^ c7;
  int vb[4];
  #pragma unroll
  for (int t = 0; t < 4; ++t)
    vb[t] = col * 128 + (qd & 1) * 8 + ((vq ^ (2 * t)) * 16);

  // negm init +100: first tile st = s+100 finite, mr>0 forced; alpha flushes to 0
  floatx4 negm[2] = {{100.f, 100.f, 100.f, 100.f}, {100.f, 100.f, 100.f, 100.f}};
  const floatx4 z4 = {0.f, 0.f, 0.f, 0.f};
  floatx4 ol[2] = {z4, z4};
  floatx4 o[4][2];
  #pragma unroll
  for (int dt = 0; dt < 4; ++dt)
    #pragma unroll
    for (int qt = 0; qt < 2; ++qt) o[dt][qt] = z4;

  stage_kv(Kg, Vg, Ks, Vs, 0, tid);
  __syncthreads();

  for (int jj = 0; jj < 2048; jj += 128) {
    attn_body<0>(jj + 64,  Kg, Vg, Ks, Vs, tid, qf, kb0, kb1, vb, negm, ol, o);
    attn_body<1>(jj + 128, Kg, Vg, Ks, Vs, tid, qf, kb0, kb1, vb, negm, ol, o);
  }

  // epilogue: l comes out of the ones-MFMA accumulator (all 4 regs equal, col=q)
  const int b = bh / 12, h = bh % 12;
  #pragma unroll
  for (int qt = 0; qt < 2; ++qt) {
    float inv = 1.0f / ol[qt][0];
    int qg = q0 + w * 32 + qt * 16 + col;
    float* obase = out + ((size_t)b * 2048 + qg) * 768 + h * 64;
    #pragma unroll
    for (int dt = 0; dt < 4; ++dt) {
      floatx4 v = o[dt][qt];
      v *= inv;
      *(floatx4*)(obase + dt * 16 + qd * 4) = v;
    }
  }
}

// ---------------- launcher ----------------
extern "C" void kernel_launch(void* const* d_in, const int* in_sizes, int n_in,
                              void* d_out, int out_size, void* d_ws, size_t ws_size,
                              hipStream_t stream) {
  const float* q  = (const float*)d_in[0];
  const float* k  = (const float*)d_in[1];
  const float* v  = (const float*)d_in[2];
  const float* Wq = (const float*)d_in[3];
  const float* bq = (const float*)d_in[4];
  const float* Wk = (const float*)d_in[5];
  const float* bk = (const float*)d_in[6];
  const float* Wv = (const float*)d_in[7];
  const float* bv = (const float*)d_in[8];

  const size_t NX = 6291456;   // 4*2048*768
  const size_t NW = 589824;    // 768*768
  const size_t need = (3 * NW + 3 * NX) * sizeof(_Float16);
  if (ws_size < need) return;

  _Float16* wh = (_Float16*)d_ws;            // [3][768][768] f16 weights
  _Float16* qh = wh + 3 * NW;                // Q' [48][2048][64] (log2e-scaled)
  _Float16* kh = qh + NX;                    // K' [48][2048][64]
  _Float16* vt = kh + NX;                    // V'^T [48][64][2048]

  CvtArgs ca;
  ca.src[0] = Wq; ca.src[1] = Wk; ca.src[2] = Wv;
  ca.dst[0] = wh; ca.dst[1] = wh + NW; ca.dst[2] = wh + 2 * NW;

  cvt_kernel<<<dim3(288, 3), 256, 0, stream>>>(ca);
  qkv_gemm<<<dim3(64, 6, 3), 256, 0, stream>>>(q, k, v, wh, bq, bk, bv, qh, kh, vt);
  attn_kernel<<<dim3(16, 48), 256, 0, stream>>>(qh, kh, vt, (float*)d_out);
}

// Round 7
// 254.839 us; speedup vs baseline: 1.0512x; 1.0512x over previous
//
#include <hip/hip_runtime.h>
#include <stdint.h>

typedef _Float16 half8  __attribute__((ext_vector_type(8)));
typedef _Float16 half4v __attribute__((ext_vector_type(4)));
typedef float    floatx4 __attribute__((ext_vector_type(4)));

#define LOG2E 1.44269504088896340736f

// async global->LDS 16B copy (LDS dest must be wave-uniform base + lane*16)
__device__ __forceinline__ void gl_lds16(const _Float16* g, _Float16* l) {
  __builtin_amdgcn_global_load_lds(
      (__attribute__((address_space(1))) void*)g,
      (__attribute__((address_space(3))) void*)l, 16, 0, 0);
}
__device__ __forceinline__ void gl_lds16f(const float* g, float* l) {
  __builtin_amdgcn_global_load_lds(
      (__attribute__((address_space(1))) void*)g,
      (__attribute__((address_space(3))) void*)l, 16, 0, 0);
}

__device__ __forceinline__ half4v pack4(float a, float b, float c, float d) {
  auto lo = __builtin_amdgcn_cvt_pkrtz(a, b);
  auto hi = __builtin_amdgcn_cvt_pkrtz(c, d);
  return half4v{static_cast<_Float16>(lo[0]), static_cast<_Float16>(lo[1]),
                static_cast<_Float16>(hi[0]), static_cast<_Float16>(hi[1])};
}
__device__ __forceinline__ half8 cvt8(floatx4 a, floatx4 b) {
  half4v lo = pack4(a[0], a[1], a[2], a[3]);
  half4v hi = pack4(b[0], b[1], b[2], b[3]);
  return __builtin_shufflevector(lo, hi, 0, 1, 2, 3, 4, 5, 6, 7);
}

// ---------------- kernel 1: fp32 -> f16 convert (weights only) ----------------
struct CvtArgs {
  const float* src[3];
  _Float16*    dst[3];
};

__global__ void cvt_kernel(CvtArgs a) {
  const int z = blockIdx.y;
  const int i = (blockIdx.x * 256 + threadIdx.x) * 8;
  const float4* s = (const float4*)(a.src[z] + i);
  float4 v0 = s[0], v1 = s[1];
  half8 h = { (_Float16)v0.x, (_Float16)v0.y, (_Float16)v0.z, (_Float16)v0.w,
              (_Float16)v1.x, (_Float16)v1.y, (_Float16)v1.z, (_Float16)v1.w };
  *(half8*)(a.dst[z] + i) = h;
}

// ---------------- kernel 2: QKV projection GEMM -----------------
// C[m,n] = X[m,:] . W[n,:] + b[n]; X staged fp32 (converted in-register),
// W staged f16, XOR-granule-swizzled LDS, double-buffered K-loop.
// Epilogue goes THROUGH LDS (stride-160 rows) so all global writes are
// coalesced 16B/lane (previous direct stores were 8B scatters with 4-8x
// DRAM write amplification).
// z=0: Q -> [48][2048][64]*log2e ; z=1: K ; z=2: V^T [48][64][2048].

__device__ __forceinline__ void gemm_stage(const float* __restrict__ X,
                                           const _Float16* __restrict__ W,
                                           float* Asb, _Float16* Bsb,
                                           int m0, int n0, int k0, int tid) {
  #pragma unroll
  for (int i = 0; i < 4; ++i) {          // A: 128 rows x 32 fp32 = 16KB
    int G = i * 256 + tid;
    int r = G >> 3, gl = G & 7;
    int g = gl ^ (r & 7);
    gl_lds16f(X + (size_t)(m0 + r) * 768 + k0 + g * 4, Asb + G * 4);
  }
  #pragma unroll
  for (int i = 0; i < 2; ++i) {          // B: 128 rows x 32 f16 = 8KB
    int G = i * 256 + tid;
    int r = G >> 2, gl = G & 3;
    int g = gl ^ ((r >> 1) & 3);
    gl_lds16(W + (size_t)(n0 + r) * 768 + k0 + g * 8, Bsb + G * 8);
  }
}

template <int BUF>
__device__ __forceinline__ void gemm_body(
    int knext, const float* __restrict__ X, const _Float16* __restrict__ W,
    float* As, _Float16* Bs, int m0, int n0, int tid, int z,
    int wr, int wc, int qd, int col, floatx4 (&acc)[4][4])
{
  if (knext < 768)
    gemm_stage(X, W, As + (1 - BUF) * 4096, Bs + (1 - BUF) * 4096, m0, n0, knext, tid);

  half8 af[4], bf[4];
  #pragma unroll
  for (int t = 0; t < 4; ++t) {
    int ra = wr * 64 + t * 16 + col;
    const float* Ab = As + BUF * 4096 + ra * 32;
    floatx4 a0 = *(const floatx4*)(Ab + (((2 * qd)     ^ (ra & 7)) * 4));
    floatx4 a1 = *(const floatx4*)(Ab + (((2 * qd + 1) ^ (ra & 7)) * 4));
    af[t] = cvt8(a0, a1);
  }
  #pragma unroll
  for (int t = 0; t < 4; ++t) {
    int rb = wc * 64 + t * 16 + col;
    bf[t] = *(const half8*)(Bs + BUF * 4096 + rb * 32 + ((qd ^ ((rb >> 1) & 3)) * 8));
  }
  if (z == 2) {
    #pragma unroll
    for (int i = 0; i < 4; ++i)
      #pragma unroll
      for (int j = 0; j < 4; ++j)
        acc[i][j] = __builtin_amdgcn_mfma_f32_16x16x32_f16(af[i], bf[j], acc[i][j], 0, 0, 0);
  } else {
    #pragma unroll
    for (int i = 0; i < 4; ++i)
      #pragma unroll
      for (int j = 0; j < 4; ++j)
        acc[i][j] = __builtin_amdgcn_mfma_f32_16x16x32_f16(bf[j], af[i], acc[i][j], 0, 0, 0);
  }
  __syncthreads();
}

__global__ __launch_bounds__(256, 2) void qkv_gemm(
    const float* __restrict__ qx, const float* __restrict__ kx, const float* __restrict__ vx,
    const _Float16* __restrict__ wh,
    const float* __restrict__ bqp, const float* __restrict__ bkp, const float* __restrict__ bvp,
    _Float16* __restrict__ oq, _Float16* __restrict__ ok, _Float16* __restrict__ ovt)
{
  __shared__ __attribute__((aligned(16))) char smem[49152];
  float*    As = (float*)smem;                    // 2*4096 fp32 = 32 KB
  _Float16* Bs = (_Float16*)(smem + 32768);       // 2*4096 f16  = 16 KB
  _Float16* Es = (_Float16*)smem;                 // epilogue 128 rows x 160 halfs = 40 KB

  const int z  = blockIdx.z;
  const float* X = (z == 0) ? qx : ((z == 1) ? kx : vx);
  const _Float16* W = wh + (size_t)z * 589824;
  const int m0 = blockIdx.x * 128, n0 = blockIdx.y * 128;
  const int tid  = threadIdx.x;
  const int lane = tid & 63, wid = tid >> 6;
  const int wr = wid >> 1, wc = wid & 1;
  const int qd = lane >> 4, col = lane & 15;

  const floatx4 z4 = {0.f, 0.f, 0.f, 0.f};
  floatx4 acc[4][4];
  #pragma unroll
  for (int i = 0; i < 4; ++i)
    #pragma unroll
    for (int j = 0; j < 4; ++j) acc[i][j] = z4;

  gemm_stage(X, W, As, Bs, m0, n0, 0, tid);
  __syncthreads();
  for (int kk = 0; kk < 768; kk += 64) {
    gemm_body<0>(kk + 32, X, W, As, Bs, m0, n0, tid, z, wr, wc, qd, col, acc);
    gemm_body<1>(kk + 64, X, W, As, Bs, m0, n0, tid, z, wr, wc, qd, col, acc);
  }
  // last gemm_body ended with __syncthreads: As/Bs dead, Es reusable

  const float* bias = (z == 0) ? bqp : ((z == 1) ? bkp : bvp);
  const int b = m0 >> 11, s0 = m0 & 2047;   // 128-row tile never crosses a batch
  if (z == 2) {
    // acc D[m(s)][n]: reg=4 consecutive s, col=n. Stage Es[n][s], copy coalesced.
    #pragma unroll
    for (int j = 0; j < 4; ++j) {
      int n_loc = wc * 64 + j * 16 + col;
      float bb = bias[n0 + n_loc];
      #pragma unroll
      for (int i = 0; i < 4; ++i) {
        int s_loc = wr * 64 + i * 16 + qd * 4;
        half4v h = pack4(acc[i][j][0] + bb, acc[i][j][1] + bb,
                         acc[i][j][2] + bb, acc[i][j][3] + bb);
        *(half4v*)(Es + n_loc * 160 + s_loc) = h;
      }
    }
    __syncthreads();
    #pragma unroll
    for (int it = 0; it < 8; ++it) {
      int row = it * 16 + (tid >> 4);          // n index 0..127
      int k   = tid & 15;                      // 16B chunk within 128 s
      half8 vr = *(const half8*)(Es + row * 160 + k * 8);
      *(half8*)(ovt + ((size_t)(b * 768 + n0 + row)) * 2048 + s0 + k * 8) = vr;
    }
  } else {
    // swapped acc D[n][s]: reg=4 consecutive n(d), col=s. Stage Es[s][n], copy coalesced.
    _Float16* O = (z == 0) ? oq : ok;
    const float scale = (z == 0) ? LOG2E : 1.0f;  // fold log2e into Q for exp2-domain softmax
    #pragma unroll
    for (int j = 0; j < 4; ++j) {
      int n_loc = wc * 64 + j * 16 + qd * 4;
      float4 bb = *(const float4*)(bias + n0 + n_loc);
      #pragma unroll
      for (int i = 0; i < 4; ++i) {
        int s_loc = wr * 64 + i * 16 + col;
        half4v h = pack4((acc[i][j][0] + bb.x) * scale, (acc[i][j][1] + bb.y) * scale,
                         (acc[i][j][2] + bb.z) * scale, (acc[i][j][3] + bb.w) * scale);
        *(half4v*)(Es + s_loc * 160 + n_loc) = h;
      }
    }
    __syncthreads();
    const int hh0 = n0 >> 6;
    #pragma unroll
    for (int it = 0; it < 8; ++it) {
      int seg = it * 32 + (tid >> 3);          // 256 segments: (s, head-half)
      int s = seg >> 1, hseg = seg & 1;
      int k = tid & 7;
      half8 vr = *(const half8*)(Es + s * 160 + hseg * 64 + k * 8);
      int mb = (m0 + s) >> 11, sg = (m0 + s) & 2047;
      *(half8*)(O + (size_t)(mb * 12 + hh0 + hseg) * 131072
                  + (size_t)sg * 64 + k * 8) = vr;
    }
  }
}

// ---------------- kernel 3: flash attention -----------------
// S^T = K.Q^T with C pre-seeded with -m (negm). pf = exp2(st - mr) on a single
// path (mr usually 0); rare-max branch only rescales live regs. l rides the MFMA
// pipe as a ones-row 16x16x16 accumulator. PV B-operand == S^T C-layout.
// Grid (48,16): bh = blockIdx.x so all 16 q-blocks of a head land on one XCD
// (dispatch d%8 == bh%8 since 48%8==0) -> K/V stay in that XCD's L2.

__device__ __forceinline__ void stage_kv(const _Float16* __restrict__ Kg,
                                         const _Float16* __restrict__ Vg,
                                         _Float16* ksd, _Float16* vsd, int j0, int tid) {
  #pragma unroll
  for (int i = 0; i < 2; ++i) {
    int c = i * 256 + tid;
    int row = c >> 3, sc = c & 7;
    gl_lds16(Kg + (size_t)(j0 + row) * 64 + ((sc ^ (row & 7)) * 8), ksd + c * 8);
    gl_lds16(Vg + (size_t)row * 2048 + j0 + ((sc ^ (row & 7)) * 8), vsd + c * 8);
  }
}

template <int BUF>
__device__ __forceinline__ void attn_body(
    int jnext, const _Float16* __restrict__ Kg, const _Float16* __restrict__ Vg,
    _Float16* Ks, _Float16* Vs, int tid,
    const half8 (&qf)[2][2], int kb0, int kb1, const int (&vb)[4],
    floatx4 (&negm)[2], floatx4 (&ol)[2], floatx4 (&o)[4][2])
{
  if (jnext < 2048)
    stage_kv(Kg, Vg, Ks + (1 - BUF) * 4096, Vs + (1 - BUF) * 4096, jnext, tid);

  const char* ksb = (const char*)Ks;
  const char* vsb = (const char*)Vs;

  // S^T - m = K . Q^T + (-m) : C seeded with negm, contraction d=64 in 2 steps
  floatx4 st[4][2];
  #pragma unroll
  for (int t = 0; t < 4; ++t) {
    half8 kf0 = *(const half8*)(ksb + BUF * 8192 + t * 2048 + kb0);
    half8 kf1 = *(const half8*)(ksb + BUF * 8192 + t * 2048 + kb1);
    #pragma unroll
    for (int qt = 0; qt < 2; ++qt) {
      st[t][qt] = __builtin_amdgcn_mfma_f32_16x16x32_f16(kf0, qf[qt][0], negm[qt], 0, 0, 0);
      st[t][qt] = __builtin_amdgcn_mfma_f32_16x16x32_f16(kf1, qf[qt][1], st[t][qt], 0, 0, 0);
    }
  }

  // tile max of (s - m); mr>0 only when running max must update (rare after warm-up)
  float mr[2];
  #pragma unroll
  for (int qt = 0; qt < 2; ++qt) {
    float v = fmaxf(
        fmaxf(fmaxf(fmaxf(st[0][qt][0], st[0][qt][1]), fmaxf(st[0][qt][2], st[0][qt][3])),
              fmaxf(fmaxf(st[1][qt][0], st[1][qt][1]), fmaxf(st[1][qt][2], st[1][qt][3]))),
        fmaxf(fmaxf(fmaxf(st[2][qt][0], st[2][qt][1]), fmaxf(st[2][qt][2], st[2][qt][3])),
              fmaxf(fmaxf(st[3][qt][0], st[3][qt][1]), fmaxf(st[3][qt][2], st[3][qt][3]))));
    v = fmaxf(v, __shfl_xor(v, 16, 64));
    v = fmaxf(v, __shfl_xor(v, 32, 64));
    mr[qt] = fmaxf(v, 0.f);
  }

  // single pf path (consumes st immediately; mr is usually 0)
  half4v pf[4][2];
  #pragma unroll
  for (int qt = 0; qt < 2; ++qt)
    #pragma unroll
    for (int t = 0; t < 4; ++t)
      pf[t][qt] = pack4(__builtin_amdgcn_exp2f(st[t][qt][0] - mr[qt]),
                        __builtin_amdgcn_exp2f(st[t][qt][1] - mr[qt]),
                        __builtin_amdgcn_exp2f(st[t][qt][2] - mr[qt]),
                        __builtin_amdgcn_exp2f(st[t][qt][3] - mr[qt]));

  // rare rescale: touches only already-live registers
  if (__any(mr[0] > 0.f || mr[1] > 0.f)) {
    #pragma unroll
    for (int qt = 0; qt < 2; ++qt) {
      float al = __builtin_amdgcn_exp2f(-mr[qt]);
      negm[qt] -= mr[qt];
      ol[qt] *= al;
      #pragma unroll
      for (int dt = 0; dt < 4; ++dt) o[dt][qt] *= al;
    }
  }

  // PV: out^T = V^T . P (K=16, P straight from regs) + ones-row MFMA accumulates l
  const half4v vone = {(_Float16)1.0f, (_Float16)1.0f, (_Float16)1.0f, (_Float16)1.0f};
  #pragma unroll
  for (int dt = 0; dt < 4; ++dt) {
    #pragma unroll
    for (int t = 0; t < 4; ++t) {
      half4v vf = *(const half4v*)(vsb + BUF * 8192 + dt * 2048 + vb[t]);
      #pragma unroll
      for (int qt = 0; qt < 2; ++qt)
        o[dt][qt] = __builtin_amdgcn_mfma_f32_16x16x16f16(vf, pf[t][qt], o[dt][qt], 0, 0, 0);
    }
  }
  #pragma unroll
  for (int t = 0; t < 4; ++t)
    #pragma unroll
    for (int qt = 0; qt < 2; ++qt)
      ol[qt] = __builtin_amdgcn_mfma_f32_16x16x16f16(vone, pf[t][qt], ol[qt], 0, 0, 0);

  __syncthreads();
}

__global__ __launch_bounds__(256, 3) void attn_kernel(
    const _Float16* __restrict__ Qm,   // [48][2048][64] (log2e-scaled)
    const _Float16* __restrict__ Km,   // [48][2048][64]
    const _Float16* __restrict__ Vt,   // [48][64][2048]
    float* __restrict__ out)           // [4][2048][768]
{
  __shared__ __attribute__((aligned(16))) _Float16 Ks[2 * 4096];
  __shared__ __attribute__((aligned(16))) _Float16 Vs[2 * 4096];
  const int bh = blockIdx.x;                 // XCD = bh % 8 (48 % 8 == 0)
  const int q0 = blockIdx.y * 128;
  const int tid = threadIdx.x, lane = tid & 63, w = tid >> 6;
  const int qd = lane >> 4, col = lane & 15, c7 = col & 7;
  const _Float16* Qg = Qm + (size_t)bh * 131072;
  const _Float16* Kg = Km + (size_t)bh * 131072;
  const _Float16* Vg = Vt + (size_t)bh * 131072;

  // Q fragments direct from global (kept in regs for the whole kernel)
  half8 qf[2][2];
  #pragma unroll
  for (int qt = 0; qt < 2; ++qt)
    #pragma unroll
    for (int ks = 0; ks < 2; ++ks)
      qf[qt][ks] = *(const half8*)(Qg + (size_t)(q0 + w * 32 + qt * 16 + col) * 64
                                   + (ks * 4 + qd) * 8);

  // loop-invariant per-lane LDS byte offsets (tile offsets fold into ds_read immediates)
  const int kb0 = col * 128 + ((qd ^ c7) * 16);
  const int kb1 = col * 128 + (((4 + qd) ^ c7) * 16);
  const int vq = (qd >> 1) ^ c7;
  int vb[4];
  #pragma unroll
  for (int t = 0; t < 4; ++t)
    vb[t] = col * 128 + (qd & 1) * 8 + ((vq ^ (2 * t)) * 16);

  // negm init +100: first tile st = s+100 finite, mr>0 forced; alpha flushes to 0
  floatx4 negm[2] = {{100.f, 100.f, 100.f, 100.f}, {100.f, 100.f, 100.f, 100.f}};
  const floatx4 z4 = {0.f, 0.f, 0.f, 0.f};
  floatx4 ol[2] = {z4, z4};
  floatx4 o[4][2];
  #pragma unroll
  for (int dt = 0; dt < 4; ++dt)
    #pragma unroll
    for (int qt = 0; qt < 2; ++qt) o[dt][qt] = z4;

  stage_kv(Kg, Vg, Ks, Vs, 0, tid);
  __syncthreads();

  for (int jj = 0; jj < 2048; jj += 128) {
    attn_body<0>(jj + 64,  Kg, Vg, Ks, Vs, tid, qf, kb0, kb1, vb, negm, ol, o);
    attn_body<1>(jj + 128, Kg, Vg, Ks, Vs, tid, qf, kb0, kb1, vb, negm, ol, o);
  }

  // epilogue: l comes out of the ones-MFMA accumulator (all 4 regs equal, col=q)
  const int b = bh / 12, h = bh % 12;
  #pragma unroll
  for (int qt = 0; qt < 2; ++qt) {
    float inv = 1.0f / ol[qt][0];
    int qg = q0 + w * 32 + qt * 16 + col;
    float* obase = out + ((size_t)b * 2048 + qg) * 768 + h * 64;
    #pragma unroll
    for (int dt = 0; dt < 4; ++dt) {
      floatx4 v = o[dt][qt];
      v *= inv;
      *(floatx4*)(obase + dt * 16 + qd * 4) = v;
    }
  }
}

// ---------------- launcher ----------------
extern "C" void kernel_launch(void* const* d_in, const int* in_sizes, int n_in,
                              void* d_out, int out_size, void* d_ws, size_t ws_size,
                              hipStream_t stream) {
  const float* q  = (const float*)d_in[0];
  const float* k  = (const float*)d_in[1];
  const float* v  = (const float*)d_in[2];
  const float* Wq = (const float*)d_in[3];
  const float* bq = (const float*)d_in[4];
  const float* Wk = (const float*)d_in[5];
  const float* bk = (const float*)d_in[6];
  const float* Wv = (const float*)d_in[7];
  const float* bv = (const float*)d_in[8];

  const size_t NX = 6291456;   // 4*2048*768
  const size_t NW = 589824;    // 768*768
  const size_t need = (3 * NW + 3 * NX) * sizeof(_Float16);
  if (ws_size < need) return;

  _Float16* wh = (_Float16*)d_ws;            // [3][768][768] f16 weights
  _Float16* qh = wh + 3 * NW;                // Q' [48][2048][64] (log2e-scaled)
  _Float16* kh = qh + NX;                    // K' [48][2048][64]
  _Float16* vt = kh + NX;                    // V'^T [48][64][2048]

  CvtArgs ca;
  ca.src[0] = Wq; ca.src[1] = Wk; ca.src[2] = Wv;
  ca.dst[0] = wh; ca.dst[1] = wh + NW; ca.dst[2] = wh + 2 * NW;

  cvt_kernel<<<dim3(288, 3), 256, 0, stream>>>(ca);
  qkv_gemm<<<dim3(64, 6, 3), 256, 0, stream>>>(q, k, v, wh, bq, bk, bv, qh, kh, vt);
  attn_kernel<<<dim3(48, 16), 256, 0, stream>>>(qh, kh, vt, (float*)d_out);
}